// Round 1
// baseline (190.144 us; speedup 1.0000x reference)
//
#include <hip/hip_runtime.h>
#include <hip/hip_bf16.h>

#define D_MODEL 256
#define NUM_HEADS 8
#define DIM_HEAD 32
#define SEQ 4096
#define BATCH 2
#define NROWS (BATCH * SEQ)              // 8192
#define LN_EPS 1e-6f
#define MASK_BIAS -1.0e9f
#define SCALE 0.17677669529663687f      // 1/sqrt(32)
#define LOG2E 1.4426950408889634f

typedef __attribute__((ext_vector_type(8))) short short8;   // 8 bf16 (4 VGPRs)
typedef __attribute__((ext_vector_type(4))) float f32x4;    // MFMA C/D

// fp32 -> bf16 bits (RNE)
static __device__ __forceinline__ unsigned short f2b(float f) {
    union { __hip_bfloat16 b; unsigned short u; } cv;
    cv.b = __float2bfloat16(f);
    return cv.u;
}
// packed fp32 pair -> bf16x2 (RNE), lo in low 16 bits
static __device__ __forceinline__ unsigned int pk_bf16(float lo, float hi) {
    union { __hip_bfloat162 v; unsigned int u; } cv;
    cv.v = __float22bfloat162_rn(make_float2(lo, hi));
    return cv.u;
}
// raw v_exp_f32: 1 instruction (no libm fixup) — confirmed win in R12
static __device__ __forceinline__ float exp2_raw(float x) {
#if __has_builtin(__builtin_amdgcn_exp2f)
    return __builtin_amdgcn_exp2f(x);
#else
    float r;
    asm volatile("v_exp_f32 %0, %1" : "=v"(r) : "v"(x));
    return r;
#endif
}
// async global->LDS, 16B per lane; LDS dest = uniform base + lane*16
static __device__ __forceinline__ void load_lds16(const void* g, void* l) {
    __builtin_amdgcn_global_load_lds(
        (const __attribute__((address_space(1))) unsigned int*)g,
        (__attribute__((address_space(3))) unsigned int*)l, 16, 0, 0);
}

// ---------------------------------------------------------------------------
// Kernel 0: prep. Blocks 0..767: Wt[n_cat][k] = W_w[k][n] (bf16) + bias.
// Blocks 768..799: T2 = pad * (-1e9*scale*log2e).
// ---------------------------------------------------------------------------
__global__ __launch_bounds__(256) void prep_kernel(
    const float* __restrict__ Wq, const float* __restrict__ Wk,
    const float* __restrict__ Wv,
    const float* __restrict__ bq, const float* __restrict__ bk,
    const float* __restrict__ bv,
    const float* __restrict__ pad,
    unsigned short* __restrict__ Wt, float* __restrict__ biasc,
    float* __restrict__ T2)
{
    const int blk = blockIdx.x;
    const int t = threadIdx.x;
    if (blk < 768) {
        const int w = blk >> 8;          // 0=Q 1=K 2=V
        const int k = blk & 255;         // input row (contraction index)
        const float* W = (w == 0) ? Wq : (w == 1) ? Wk : Wv;
        Wt[(size_t)(w * 256 + t) * 256 + k] = f2b(W[(size_t)k * 256 + t]);
        if (k == 0) {
            const float* bb = (w == 0) ? bq : (w == 1) ? bk : bv;
            biasc[w * 256 + t] = bb[t];
        }
    } else {
        const int i = (blk - 768) * 256 + t;
        T2[i] = pad[i] * (MASK_BIAS * SCALE * LOG2E);
    }
}

// ---------------------------------------------------------------------------
// Kernel 1: QKV projection as bf16 MFMA GEMM (unchanged from R12).
// ---------------------------------------------------------------------------
__global__ __launch_bounds__(256) void qkv_mfma_kernel(
    const float* __restrict__ x, const unsigned short* __restrict__ Wt,
    const float* __restrict__ biasc,
    unsigned short* __restrict__ Qh, unsigned short* __restrict__ Kh,
    unsigned short* __restrict__ Vt)
{
    const int lane = threadIdx.x & 63;
    const int wid  = threadIdx.x >> 6;
    const int c    = lane & 15;
    const int quad = lane >> 4;

    const int r0 = (blockIdx.x >> 3) * 64 + wid * 16;   // wave row base
    const int n0 = (blockIdx.x & 7) * 96;               // wave col base

    f32x4 acc[6];
    float bias[6];
    #pragma unroll
    for (int t = 0; t < 6; t++) {
        acc[t] = (f32x4){0.f, 0.f, 0.f, 0.f};
        bias[t] = biasc[n0 + 16 * t + c];
    }

    const float* xp0 = x + (size_t)(r0 + c) * D_MODEL + quad * 8;
    const unsigned short* wp0 = Wt + (size_t)(n0 + c) * 256 + quad * 8;

    for (int k0 = 0; k0 < 256; k0 += 32) {
        const float4 a0 = *(const float4*)(xp0 + k0);
        const float4 a1 = *(const float4*)(xp0 + k0 + 4);
        union { unsigned int u[4]; short8 s; } af;
        af.u[0] = pk_bf16(a0.x, a0.y);
        af.u[1] = pk_bf16(a0.z, a0.w);
        af.u[2] = pk_bf16(a1.x, a1.y);
        af.u[3] = pk_bf16(a1.z, a1.w);
        #pragma unroll
        for (int t = 0; t < 6; t++) {
            const short8 bf = *(const short8*)(wp0 + (size_t)(16 * t) * 256 + k0);
            acc[t] = __builtin_amdgcn_mfma_f32_16x16x32_bf16(af.s, bf, acc[t], 0, 0, 0);
        }
    }

    #pragma unroll
    for (int t = 0; t < 6; t++) {
        const int col = n0 + 16 * t;          // tile col base (multiple of 16)
        const int mm  = col >> 8;             // 0=Q 1=K 2=V (uniform per tile)
        const int dim = (col & 255) + c;
        const int h = dim >> 5, d = dim & 31;
        const int row = r0 + quad * 4;        // rows row..row+3 (same batch)
        const int bb = row >> 12;
        const int s  = row & (SEQ - 1);
        const size_t bh = (size_t)(bb * NUM_HEADS + h);
        const float v0 = acc[t][0] + bias[t];
        const float v1 = acc[t][1] + bias[t];
        const float v2 = acc[t][2] + bias[t];
        const float v3 = acc[t][3] + bias[t];
        if (mm == 2) {
            uint2 pk = make_uint2(pk_bf16(v0, v1), pk_bf16(v2, v3));
            *(uint2*)(Vt + (bh * DIM_HEAD + d) * SEQ + s) = pk;
        } else {
            unsigned short* P = (mm == 0 ? Qh : Kh) + (bh * SEQ + s) * DIM_HEAD + d;
            P[0]  = f2b(v0);
            P[32] = f2b(v1);
            P[64] = f2b(v2);
            P[96] = f2b(v3);
        }
    }
}

// ---------------------------------------------------------------------------
// Kernel 2: MFMA flash attention v6 — cooperative async LDS staging.
// Block = 64 queries (4 waves x 16q), ALL waves share every 64-key chunk.
// Chunk staged via global_load_lds (K 4KB + V 4KB + T 256B) double-buffered;
// one __syncthreads per chunk (drains vmcnt). XOR swizzle folded into the
// staging *global* addresses (LDS placement is forced linear): K dim-group
// g^f(key), f=((key>>1)^(key>>3))&3; V key-group g^(dim&7) -> <=2-way bank
// aliasing on reads (free). Math identical to R12 (perm trick, ones-MFMA
// denominator, raw v_exp_f32). No key-split => no partial combine at all.
// ---------------------------------------------------------------------------
__global__ __launch_bounds__(256, 4) void attn_mfma_kernel(
    const unsigned short* __restrict__ Qh, const unsigned short* __restrict__ Kh,
    const unsigned short* __restrict__ Vt, const float* __restrict__ T2,
    float* __restrict__ O)
{
    __shared__ __align__(16) unsigned short ldsK[2][64 * 32];  // [key][dimgrp] 2x4KB
    __shared__ __align__(16) unsigned short ldsV[2][32 * 64];  // [dim][keygrp] 2x4KB
    __shared__ __align__(16) float          ldsT[2][64];       // 2x256B

    const int lane = threadIdx.x & 63;
    const int wid  = threadIdx.x >> 6;
    const int c    = lane & 15;
    const int quad = lane >> 4;

    const int gw = blockIdx.x;                   // 0..1023
    const int q0 = (gw & 63) * 64;               // 64 queries per block
    const int h  = (gw >> 6) & (NUM_HEADS - 1);
    const int b  = gw >> 9;
    const size_t bh = (size_t)(b * NUM_HEADS + h);

    const float k2 = SCALE * LOG2E;
    const int perm = ((c & 12) << 1) | (c & 3);  // pi(c)

    const unsigned short* Kb = Kh + bh * SEQ * DIM_HEAD;
    const unsigned short* Vb = Vt + bh * DIM_HEAD * SEQ;
    const float* Tb = T2 + (size_t)b * SEQ;

    // wave's 16 queries: q0 + wid*16 + c
    const int qrow = q0 + wid * 16;
    const short8 qf = *(const short8*)(Qh + (bh * SEQ + qrow + c) * DIM_HEAD + quad * 8);

    union { unsigned int u[4]; short8 s; } ones;
    ones.u[0] = ones.u[1] = ones.u[2] = ones.u[3] = 0x3F803F80u;  // bf16 1.0 x2

    // loop-invariant LDS read offsets (elements)
    const int f0 = ((perm >> 1) ^ (perm >> 3)) & 3;
    const int f1 = (((perm + 4) >> 1) ^ ((perm + 4) >> 3)) & 3;
    const int kA = perm * 32 + ((quad ^ f0) << 3);        // + sub*1024
    const int kB = (perm + 4) * 32 + ((quad ^ f1) << 3);
    const int g0 = quad ^ (c & 7);
    const int vA0 = c * 64 + (g0 << 3);
    const int vA1 = c * 64 + ((g0 ^ 4) << 3);
    const int vB0 = (16 + c) * 64 + (g0 << 3);
    const int vB1 = (16 + c) * 64 + ((g0 ^ 4) << 3);

    // staging lane constants
    const int skey = (lane >> 2);                // + j*16
    const int sgK  = lane & 3;
    const int sdim = lane >> 3;                  // + j*8
    const int sgV  = lane & 7;

    f32x4 o0 = {0.f,0.f,0.f,0.f}, o1 = {0.f,0.f,0.f,0.f};
    f32x4 lacc = {0.f,0.f,0.f,0.f};
    const f32x4 z = {0.f, 0.f, 0.f, 0.f};

    // stage chunk ch into buffer pb (wave-split: w0/w1 -> K, w2/w3 -> V(+T))
    auto stage = [&](int ch, int pb) {
        const int s0 = ch * 64;
        if (wid < 2) {
            #pragma unroll
            for (int jj = 0; jj < 2; jj++) {
                const int j = wid * 2 + jj;
                const int key = j * 16 + skey;
                const int f = ((key >> 1) ^ (key >> 3)) & 3;
                load_lds16(Kb + (size_t)(s0 + key) * 32 + ((sgK ^ f) << 3),
                           &ldsK[pb][j * 512]);
            }
        } else {
            #pragma unroll
            for (int jj = 0; jj < 2; jj++) {
                const int j = (wid - 2) * 2 + jj;
                const int dim = j * 8 + sdim;
                load_lds16(Vb + (size_t)dim * SEQ + s0 + ((sgV ^ (dim & 7)) << 3),
                           &ldsV[pb][j * 512]);
            }
            if (wid == 3 && lane < 16)
                load_lds16(Tb + s0 + lane * 4, &ldsT[pb][0]);
        }
    };

    // one 32-key sub-chunk from LDS buffer pb
    auto sub = [&](int pb, int s) {
        const short8 kf0 = *(const short8*)&ldsK[pb][s * 1024 + kA];
        const short8 kf1 = *(const short8*)&ldsK[pb][s * 1024 + kB];
        const short8 vf0 = *(const short8*)&ldsV[pb][s ? vA1 : vA0];
        const short8 vf1 = *(const short8*)&ldsV[pb][s ? vB1 : vB0];
        const float4 t0 = *(const float4*)&ldsT[pb][s * 32 + quad * 8];
        const float4 t1 = *(const float4*)&ldsT[pb][s * 32 + quad * 8 + 4];

        const f32x4 st0 = __builtin_amdgcn_mfma_f32_16x16x32_bf16(kf0, qf, z, 0, 0, 0);
        const f32x4 st1 = __builtin_amdgcn_mfma_f32_16x16x32_bf16(kf1, qf, z, 0, 0, 0);

        float p[8];
        p[0] = exp2_raw(fmaf(st0[0], k2, t0.x));
        p[1] = exp2_raw(fmaf(st0[1], k2, t0.y));
        p[2] = exp2_raw(fmaf(st0[2], k2, t0.z));
        p[3] = exp2_raw(fmaf(st0[3], k2, t0.w));
        p[4] = exp2_raw(fmaf(st1[0], k2, t1.x));
        p[5] = exp2_raw(fmaf(st1[1], k2, t1.y));
        p[6] = exp2_raw(fmaf(st1[2], k2, t1.z));
        p[7] = exp2_raw(fmaf(st1[3], k2, t1.w));

        union { unsigned int u[4]; short8 s8; } pf;
        pf.u[0] = pk_bf16(p[0], p[1]);
        pf.u[1] = pk_bf16(p[2], p[3]);
        pf.u[2] = pk_bf16(p[4], p[5]);
        pf.u[3] = pk_bf16(p[6], p[7]);

        lacc = __builtin_amdgcn_mfma_f32_16x16x32_bf16(ones.s, pf.s8, lacc, 0, 0, 0);
        o0   = __builtin_amdgcn_mfma_f32_16x16x32_bf16(vf0,   pf.s8, o0,   0, 0, 0);
        o1   = __builtin_amdgcn_mfma_f32_16x16x32_bf16(vf1,   pf.s8, o1,   0, 0, 0);
    };

    stage(0, 0);
    __syncthreads();
    for (int ch = 0; ch < SEQ / 64; ++ch) {
        const int pb = ch & 1;
        stage((ch + 1) & 63, pb ^ 1);    // async prefetch into other buffer
        sub(pb, 0);
        sub(pb, 1);
        __syncthreads();                 // drains vmcnt; fences both buffers
    }

    // normalize + store: every lane's lacc[0] = denominator of query col c
    const float inv = 1.0f / lacc[0];
    float* op = O + ((size_t)(b * SEQ) + qrow + c) * D_MODEL + h * DIM_HEAD + quad * 4;
    *(float4*)op        = make_float4(o0[0]*inv, o0[1]*inv, o0[2]*inv, o0[3]*inv);
    *(float4*)(op + 16) = make_float4(o1[0]*inv, o1[1]*inv, o1[2]*inv, o1[3]*inv);
}

// ---------------------------------------------------------------------------
// Kernel 3: residual add + LayerNorm IN PLACE on d_out (fp32 -> fp32).
// ---------------------------------------------------------------------------
__global__ __launch_bounds__(256) void ln_kernel(
    float* AO,                     // aliased read A / write out — no restrict
    const float* __restrict__ x,
    const float* __restrict__ gamma, const float* __restrict__ beta)
{
    const int lane = threadIdx.x & 63;
    const int wid  = threadIdx.x >> 6;
    const size_t row = (size_t)blockIdx.x * 4 + wid;

    const float4 a  = ((const float4*)(AO + row * D_MODEL))[lane];
    const float4 xv = ((const float4*)(x + row * D_MODEL))[lane];
    float hv[4];
    hv[0] = a.x + xv.x;
    hv[1] = a.y + xv.y;
    hv[2] = a.z + xv.z;
    hv[3] = a.w + xv.w;

    float s = hv[0] + hv[1] + hv[2] + hv[3];
    #pragma unroll
    for (int off = 32; off > 0; off >>= 1) s += __shfl_xor(s, off, 64);
    const float mu = s * (1.0f / D_MODEL);

    float d0 = hv[0]-mu, d1 = hv[1]-mu, d2 = hv[2]-mu, d3 = hv[3]-mu;
    float ss = d0*d0 + d1*d1 + d2*d2 + d3*d3;
    #pragma unroll
    for (int off = 32; off > 0; off >>= 1) ss += __shfl_xor(ss, off, 64);
    const float rs = rsqrtf(ss * (1.0f / D_MODEL) + LN_EPS);

    const float4 g  = ((const float4*)gamma)[lane];
    const float4 bb = ((const float4*)beta)[lane];
    float4 y;
    y.x = g.x * d0 * rs + bb.x;
    y.y = g.y * d1 * rs + bb.y;
    y.z = g.z * d2 * rs + bb.z;
    y.w = g.w * d3 * rs + bb.w;
    ((float4*)(AO + row * D_MODEL))[lane] = y;
}

// ---------------------------------------------------------------------------
extern "C" void kernel_launch(void* const* d_in, const int* in_sizes, int n_in,
                              void* d_out, int out_size, void* d_ws, size_t ws_size,
                              hipStream_t stream)
{
    const float* x     = (const float*)d_in[0];
    const float* pad   = (const float*)d_in[1];
    const float* Wq    = (const float*)d_in[2];
    const float* bq    = (const float*)d_in[3];
    const float* Wk    = (const float*)d_in[4];
    const float* bk    = (const float*)d_in[5];
    const float* Wv    = (const float*)d_in[6];
    const float* bv    = (const float*)d_in[7];
    const float* gamma = (const float*)d_in[8];
    const float* beta  = (const float*)d_in[9];

    const size_t elems = (size_t)NROWS * D_MODEL;       // 2M
    unsigned short* Qh = (unsigned short*)d_ws;          // 4 MB
    unsigned short* Kh = Qh + elems;                     // 4 MB
    unsigned short* Vt = Kh + elems;                     // 4 MB
    float* T2 = (float*)(Vt + elems);                    // 32 KB
    unsigned short* Wt = (unsigned short*)(T2 + NROWS);  // 768x256 bf16, 384 KB
    float* biasc = (float*)(Wt + 768 * 256);             // 3 KB
    float* AO = (float*)d_out;                           // attn out + final out

    prep_kernel<<<800, 256, 0, stream>>>(Wq, Wk, Wv, bq, bk, bv, pad,
                                         Wt, biasc, T2);
    qkv_mfma_kernel<<<(NROWS / 64) * 8, 256, 0, stream>>>(x, Wt, biasc,
                                                          Qh, Kh, Vt);
    attn_mfma_kernel<<<BATCH * NUM_HEADS * (SEQ / 64), 256, 0, stream>>>(
        Qh, Kh, Vt, T2, AO);
    ln_kernel<<<NROWS / 4, 256, 0, stream>>>(AO, x, gamma, beta);
}

// Round 2
// 178.526 us; speedup vs baseline: 1.0651x; 1.0651x over previous
//
#include <hip/hip_runtime.h>
#include <hip/hip_bf16.h>

#define D_MODEL 256
#define NUM_HEADS 8
#define DIM_HEAD 32
#define SEQ 4096
#define BATCH 2
#define NROWS (BATCH * SEQ)              // 8192
#define LN_EPS 1e-6f
#define MASK_BIAS -1.0e9f
#define SCALE 0.17677669529663687f      // 1/sqrt(32)
#define LOG2E 1.4426950408889634f
#define QSCALE (SCALE * LOG2E)          // folded into Q at projection time

typedef __attribute__((ext_vector_type(8))) short short8;   // 8 bf16 (4 VGPRs)
typedef __attribute__((ext_vector_type(4))) float f32x4;    // MFMA C/D

// fp32 -> bf16 bits (RNE)
static __device__ __forceinline__ unsigned short f2b(float f) {
    union { __hip_bfloat16 b; unsigned short u; } cv;
    cv.b = __float2bfloat16(f);
    return cv.u;
}
// packed fp32 pair -> bf16x2 (RNE), lo in low 16 bits
static __device__ __forceinline__ unsigned int pk_bf16(float lo, float hi) {
    union { __hip_bfloat162 v; unsigned int u; } cv;
    cv.v = __float22bfloat162_rn(make_float2(lo, hi));
    return cv.u;
}
// raw v_exp_f32: 1 instruction (no libm fixup)
static __device__ __forceinline__ float exp2_raw(float x) {
#if __has_builtin(__builtin_amdgcn_exp2f)
    return __builtin_amdgcn_exp2f(x);
#else
    float r;
    asm volatile("v_exp_f32 %0, %1" : "=v"(r) : "v"(x));
    return r;
#endif
}
// async global->LDS, 16B per lane; LDS dest = uniform base + lane*16
static __device__ __forceinline__ void load_lds16(const void* g, void* l) {
    __builtin_amdgcn_global_load_lds(
        (const __attribute__((address_space(1))) unsigned int*)g,
        (__attribute__((address_space(3))) unsigned int*)l, 16, 0, 0);
}

// ---------------------------------------------------------------------------
// Kernel 0: prep. Blocks 0..767: Wt[n_cat][k] = W_w[k][n] (bf16) + bias.
// Blocks 768..799: T2 = pad * (-1e9*scale*log2e).
// ---------------------------------------------------------------------------
__global__ __launch_bounds__(256) void prep_kernel(
    const float* __restrict__ Wq, const float* __restrict__ Wk,
    const float* __restrict__ Wv,
    const float* __restrict__ bq, const float* __restrict__ bk,
    const float* __restrict__ bv,
    const float* __restrict__ pad,
    unsigned short* __restrict__ Wt, float* __restrict__ biasc,
    float* __restrict__ T2)
{
    const int blk = blockIdx.x;
    const int t = threadIdx.x;
    if (blk < 768) {
        const int w = blk >> 8;          // 0=Q 1=K 2=V
        const int k = blk & 255;         // input row (contraction index)
        const float* W = (w == 0) ? Wq : (w == 1) ? Wk : Wv;
        Wt[(size_t)(w * 256 + t) * 256 + k] = f2b(W[(size_t)k * 256 + t]);
        if (k == 0) {
            const float* bb = (w == 0) ? bq : (w == 1) ? bk : bv;
            biasc[w * 256 + t] = bb[t];
        }
    } else {
        const int i = (blk - 768) * 256 + t;
        T2[i] = pad[i] * (MASK_BIAS * SCALE * LOG2E);
    }
}

// ---------------------------------------------------------------------------
// Kernel 1: QKV projection as bf16 MFMA GEMM.
// R13 change: Q output is pre-scaled by QSCALE = SCALE*LOG2E, so the attn
// kernel's QK^T MFMA result is already in exp2-argument units.
// ---------------------------------------------------------------------------
__global__ __launch_bounds__(256) void qkv_mfma_kernel(
    const float* __restrict__ x, const unsigned short* __restrict__ Wt,
    const float* __restrict__ biasc,
    unsigned short* __restrict__ Qh, unsigned short* __restrict__ Kh,
    unsigned short* __restrict__ Vt)
{
    const int lane = threadIdx.x & 63;
    const int wid  = threadIdx.x >> 6;
    const int c    = lane & 15;
    const int quad = lane >> 4;

    const int r0 = (blockIdx.x >> 3) * 64 + wid * 16;   // wave row base
    const int n0 = (blockIdx.x & 7) * 96;               // wave col base

    f32x4 acc[6];
    float bias[6];
    #pragma unroll
    for (int t = 0; t < 6; t++) {
        acc[t] = (f32x4){0.f, 0.f, 0.f, 0.f};
        bias[t] = biasc[n0 + 16 * t + c];
    }

    const float* xp0 = x + (size_t)(r0 + c) * D_MODEL + quad * 8;
    const unsigned short* wp0 = Wt + (size_t)(n0 + c) * 256 + quad * 8;

    for (int k0 = 0; k0 < 256; k0 += 32) {
        const float4 a0 = *(const float4*)(xp0 + k0);
        const float4 a1 = *(const float4*)(xp0 + k0 + 4);
        union { unsigned int u[4]; short8 s; } af;
        af.u[0] = pk_bf16(a0.x, a0.y);
        af.u[1] = pk_bf16(a0.z, a0.w);
        af.u[2] = pk_bf16(a1.x, a1.y);
        af.u[3] = pk_bf16(a1.z, a1.w);
        #pragma unroll
        for (int t = 0; t < 6; t++) {
            const short8 bf = *(const short8*)(wp0 + (size_t)(16 * t) * 256 + k0);
            acc[t] = __builtin_amdgcn_mfma_f32_16x16x32_bf16(af.s, bf, acc[t], 0, 0, 0);
        }
    }

    #pragma unroll
    for (int t = 0; t < 6; t++) {
        const int col = n0 + 16 * t;          // tile col base (multiple of 16)
        const int mm  = col >> 8;             // 0=Q 1=K 2=V (uniform per tile)
        const int dim = (col & 255) + c;
        const int h = dim >> 5, d = dim & 31;
        const int row = r0 + quad * 4;        // rows row..row+3 (same batch)
        const int bb = row >> 12;
        const int s  = row & (SEQ - 1);
        const size_t bh = (size_t)(bb * NUM_HEADS + h);
        float v0 = acc[t][0] + bias[t];
        float v1 = acc[t][1] + bias[t];
        float v2 = acc[t][2] + bias[t];
        float v3 = acc[t][3] + bias[t];
        if (mm == 2) {
            uint2 pk = make_uint2(pk_bf16(v0, v1), pk_bf16(v2, v3));
            *(uint2*)(Vt + (bh * DIM_HEAD + d) * SEQ + s) = pk;
        } else {
            if (mm == 0) {                    // pre-scale Q by SCALE*LOG2E
                v0 *= QSCALE; v1 *= QSCALE; v2 *= QSCALE; v3 *= QSCALE;
            }
            unsigned short* P = (mm == 0 ? Qh : Kh) + (bh * SEQ + s) * DIM_HEAD + d;
            P[0]  = f2b(v0);
            P[32] = f2b(v1);
            P[64] = f2b(v2);
            P[96] = f2b(v3);
        }
    }
}

// ---------------------------------------------------------------------------
// Kernel 2: MFMA flash attention v7 — triple-buffered counted-vmcnt pipeline.
// Block = 64 queries (4 waves x 16q); every 64-key chunk staged via
// global_load_lds (K 4KB + V 4KB + T 256B), prefetch distance 2 chunks.
// Per chunk: s_waitcnt vmcnt(NL) lgkmcnt(0) [NL = newest stage's loads only,
// NEVER 0] -> raw s_barrier -> stage(ch+2) -> compute(ch). The old
// __syncthreads() drained vmcnt(0), exposing full load latency each chunk.
// Mask+scale fma is now folded into the QK^T MFMA's C operand (Q pre-scaled
// by QSCALE in kernel 1; T passed as C), so p = exp2(st) directly.
// ---------------------------------------------------------------------------
__global__ __launch_bounds__(256, 4) void attn_mfma_kernel(
    const unsigned short* __restrict__ Qh, const unsigned short* __restrict__ Kh,
    const unsigned short* __restrict__ Vt, const float* __restrict__ T2,
    float* __restrict__ O)
{
    __shared__ __align__(16) unsigned short ldsK[3][64 * 32];  // [key][dimgrp] 3x4KB
    __shared__ __align__(16) unsigned short ldsV[3][32 * 64];  // [dim][keygrp] 3x4KB
    __shared__ __align__(16) float          ldsT[3][64];       // 3x256B

    const int lane = threadIdx.x & 63;
    const int wid  = threadIdx.x >> 6;
    const int c    = lane & 15;
    const int quad = lane >> 4;

    const int gw = blockIdx.x;                   // 0..1023
    const int q0 = (gw & 63) * 64;               // 64 queries per block
    const int h  = (gw >> 6) & (NUM_HEADS - 1);
    const int b  = gw >> 9;
    const size_t bh = (size_t)(b * NUM_HEADS + h);

    const int perm = ((c & 12) << 1) | (c & 3);  // pi(c)

    const unsigned short* Kb = Kh + bh * SEQ * DIM_HEAD;
    const unsigned short* Vb = Vt + bh * DIM_HEAD * SEQ;
    const float* Tb = T2 + (size_t)b * SEQ;

    // wave's 16 queries: q0 + wid*16 + c
    const int qrow = q0 + wid * 16;
    const short8 qf = *(const short8*)(Qh + (bh * SEQ + qrow + c) * DIM_HEAD + quad * 8);

    union { unsigned int u[4]; short8 s; } ones;
    ones.u[0] = ones.u[1] = ones.u[2] = ones.u[3] = 0x3F803F80u;  // bf16 1.0 x2

    // loop-invariant LDS read offsets (elements)
    const int f0 = ((perm >> 1) ^ (perm >> 3)) & 3;
    const int f1 = (((perm + 4) >> 1) ^ ((perm + 4) >> 3)) & 3;
    const int kA = perm * 32 + ((quad ^ f0) << 3);        // + sub*1024
    const int kB = (perm + 4) * 32 + ((quad ^ f1) << 3);
    const int g0 = quad ^ (c & 7);
    const int vA0 = c * 64 + (g0 << 3);
    const int vA1 = c * 64 + ((g0 ^ 4) << 3);
    const int vB0 = (16 + c) * 64 + (g0 << 3);
    const int vB1 = (16 + c) * 64 + ((g0 ^ 4) << 3);

    // staging lane constants
    const int skey = (lane >> 2);                // + j*16
    const int sgK  = lane & 3;
    const int sdim = lane >> 3;                  // + j*8
    const int sgV  = lane & 7;

    f32x4 o0 = {0.f,0.f,0.f,0.f}, o1 = {0.f,0.f,0.f,0.f};
    f32x4 lacc = {0.f,0.f,0.f,0.f};

    // stage chunk ch into buffer pb (wave-split: w0/w1 -> K, w2/w3 -> V(+T))
    // per-wave vm-op count: wid 0..2 -> 2, wid 3 -> 3
    auto stage = [&](int ch, int pb) {
        const int s0 = ch * 64;
        if (wid < 2) {
            #pragma unroll
            for (int jj = 0; jj < 2; jj++) {
                const int j = wid * 2 + jj;
                const int key = j * 16 + skey;
                const int f = ((key >> 1) ^ (key >> 3)) & 3;
                load_lds16(Kb + (size_t)(s0 + key) * 32 + ((sgK ^ f) << 3),
                           &ldsK[pb][j * 512]);
            }
        } else {
            #pragma unroll
            for (int jj = 0; jj < 2; jj++) {
                const int j = (wid - 2) * 2 + jj;
                const int dim = j * 8 + sdim;
                load_lds16(Vb + (size_t)dim * SEQ + s0 + ((sgV ^ (dim & 7)) << 3),
                           &ldsV[pb][j * 512]);
            }
            if (wid == 3 && lane < 16)
                load_lds16(Tb + s0 + lane * 4, &ldsT[pb][0]);
        }
    };

    // one 32-key sub-chunk from LDS buffer pb; T folded in as MFMA C operand
    auto sub = [&](int pb, int s) {
        const short8 kf0 = *(const short8*)&ldsK[pb][s * 1024 + kA];
        const short8 kf1 = *(const short8*)&ldsK[pb][s * 1024 + kB];
        const short8 vf0 = *(const short8*)&ldsV[pb][s ? vA1 : vA0];
        const short8 vf1 = *(const short8*)&ldsV[pb][s ? vB1 : vB0];
        const float4 t0 = *(const float4*)&ldsT[pb][s * 32 + quad * 8];
        const float4 t1 = *(const float4*)&ldsT[pb][s * 32 + quad * 8 + 4];

        const f32x4 c0 = {t0.x, t0.y, t0.z, t0.w};
        const f32x4 c1 = {t1.x, t1.y, t1.z, t1.w};
        const f32x4 st0 = __builtin_amdgcn_mfma_f32_16x16x32_bf16(kf0, qf, c0, 0, 0, 0);
        const f32x4 st1 = __builtin_amdgcn_mfma_f32_16x16x32_bf16(kf1, qf, c1, 0, 0, 0);

        float p[8];
        p[0] = exp2_raw(st0[0]);
        p[1] = exp2_raw(st0[1]);
        p[2] = exp2_raw(st0[2]);
        p[3] = exp2_raw(st0[3]);
        p[4] = exp2_raw(st1[0]);
        p[5] = exp2_raw(st1[1]);
        p[6] = exp2_raw(st1[2]);
        p[7] = exp2_raw(st1[3]);

        union { unsigned int u[4]; short8 s8; } pf;
        pf.u[0] = pk_bf16(p[0], p[1]);
        pf.u[1] = pk_bf16(p[2], p[3]);
        pf.u[2] = pk_bf16(p[4], p[5]);
        pf.u[3] = pk_bf16(p[6], p[7]);

        lacc = __builtin_amdgcn_mfma_f32_16x16x32_bf16(ones.s, pf.s8, lacc, 0, 0, 0);
        o0   = __builtin_amdgcn_mfma_f32_16x16x32_bf16(vf0,   pf.s8, o0,   0, 0, 0);
        o1   = __builtin_amdgcn_mfma_f32_16x16x32_bf16(vf1,   pf.s8, o1,   0, 0, 0);
    };

    // prologue: prefetch chunks 0 and 1
    stage(0, 0);
    stage(1, 1);

    int rb = 0;          // read buffer  = ch % 3
    int sb = 2;          // stage buffer = (ch+2) % 3
    for (int ch = 0; ch < SEQ / 64; ++ch) {
        // wait for MY stage(ch) loads (allow the newer stage(ch+1) to remain
        // in flight); lgkmcnt(0) ensures all my LDS reads of buf[(ch-1)%3]
        // executed before I arrive at the barrier.
        if (wid == 3)
            asm volatile("s_waitcnt vmcnt(3) lgkmcnt(0)" ::: "memory");
        else
            asm volatile("s_waitcnt vmcnt(2) lgkmcnt(0)" ::: "memory");
        __builtin_amdgcn_s_barrier();
        __builtin_amdgcn_sched_barrier(0);
        // all waves' stage(ch) visible; all waves done reading buf[(ch-1)%3]
        stage((ch + 2) & 63, sb);        // overwrite buf[(ch-1)%3]
        sub(rb, 0);
        sub(rb, 1);
        rb = (rb == 2) ? 0 : rb + 1;
        sb = (sb == 2) ? 0 : sb + 1;
    }

    // normalize + store: every lane's lacc[0] = denominator of query col c
    const float inv = 1.0f / lacc[0];
    float* op = O + ((size_t)(b * SEQ) + qrow + c) * D_MODEL + h * DIM_HEAD + quad * 4;
    *(float4*)op        = make_float4(o0[0]*inv, o0[1]*inv, o0[2]*inv, o0[3]*inv);
    *(float4*)(op + 16) = make_float4(o1[0]*inv, o1[1]*inv, o1[2]*inv, o1[3]*inv);
}

// ---------------------------------------------------------------------------
// Kernel 3: residual add + LayerNorm IN PLACE on d_out (fp32 -> fp32).
// ---------------------------------------------------------------------------
__global__ __launch_bounds__(256) void ln_kernel(
    float* AO,                     // aliased read A / write out — no restrict
    const float* __restrict__ x,
    const float* __restrict__ gamma, const float* __restrict__ beta)
{
    const int lane = threadIdx.x & 63;
    const int wid  = threadIdx.x >> 6;
    const size_t row = (size_t)blockIdx.x * 4 + wid;

    const float4 a  = ((const float4*)(AO + row * D_MODEL))[lane];
    const float4 xv = ((const float4*)(x + row * D_MODEL))[lane];
    float hv[4];
    hv[0] = a.x + xv.x;
    hv[1] = a.y + xv.y;
    hv[2] = a.z + xv.z;
    hv[3] = a.w + xv.w;

    float s = hv[0] + hv[1] + hv[2] + hv[3];
    #pragma unroll
    for (int off = 32; off > 0; off >>= 1) s += __shfl_xor(s, off, 64);
    const float mu = s * (1.0f / D_MODEL);

    float d0 = hv[0]-mu, d1 = hv[1]-mu, d2 = hv[2]-mu, d3 = hv[3]-mu;
    float ss = d0*d0 + d1*d1 + d2*d2 + d3*d3;
    #pragma unroll
    for (int off = 32; off > 0; off >>= 1) ss += __shfl_xor(ss, off, 64);
    const float rs = rsqrtf(ss * (1.0f / D_MODEL) + LN_EPS);

    const float4 g  = ((const float4*)gamma)[lane];
    const float4 bb = ((const float4*)beta)[lane];
    float4 y;
    y.x = g.x * d0 * rs + bb.x;
    y.y = g.y * d1 * rs + bb.y;
    y.z = g.z * d2 * rs + bb.z;
    y.w = g.w * d3 * rs + bb.w;
    ((float4*)(AO + row * D_MODEL))[lane] = y;
}

// ---------------------------------------------------------------------------
extern "C" void kernel_launch(void* const* d_in, const int* in_sizes, int n_in,
                              void* d_out, int out_size, void* d_ws, size_t ws_size,
                              hipStream_t stream)
{
    const float* x     = (const float*)d_in[0];
    const float* pad   = (const float*)d_in[1];
    const float* Wq    = (const float*)d_in[2];
    const float* bq    = (const float*)d_in[3];
    const float* Wk    = (const float*)d_in[4];
    const float* bk    = (const float*)d_in[5];
    const float* Wv    = (const float*)d_in[6];
    const float* bv    = (const float*)d_in[7];
    const float* gamma = (const float*)d_in[8];
    const float* beta  = (const float*)d_in[9];

    const size_t elems = (size_t)NROWS * D_MODEL;       // 2M
    unsigned short* Qh = (unsigned short*)d_ws;          // 4 MB
    unsigned short* Kh = Qh + elems;                     // 4 MB
    unsigned short* Vt = Kh + elems;                     // 4 MB
    float* T2 = (float*)(Vt + elems);                    // 32 KB
    unsigned short* Wt = (unsigned short*)(T2 + NROWS);  // 768x256 bf16, 384 KB
    float* biasc = (float*)(Wt + 768 * 256);             // 3 KB
    float* AO = (float*)d_out;                           // attn out + final out

    prep_kernel<<<800, 256, 0, stream>>>(Wq, Wk, Wv, bq, bk, bv, pad,
                                         Wt, biasc, T2);
    qkv_mfma_kernel<<<(NROWS / 64) * 8, 256, 0, stream>>>(x, Wt, biasc,
                                                          Qh, Kh, Vt);
    attn_mfma_kernel<<<BATCH * NUM_HEADS * (SEQ / 64), 256, 0, stream>>>(
        Qh, Kh, Vt, T2, AO);
    ln_kernel<<<NROWS / 4, 256, 0, stream>>>(AO, x, gamma, beta);
}

// Round 3
// 178.238 us; speedup vs baseline: 1.0668x; 1.0016x over previous
//
#include <hip/hip_runtime.h>
#include <hip/hip_bf16.h>

#define D_MODEL 256
#define NUM_HEADS 8
#define DIM_HEAD 32
#define SEQ 4096
#define BATCH 2
#define NROWS (BATCH * SEQ)              // 8192
#define LN_EPS 1e-6f
#define MASK_BIAS -1.0e9f
#define SCALE 0.17677669529663687f      // 1/sqrt(32)
#define LOG2E 1.4426950408889634f
#define QSCALE (SCALE * LOG2E)          // folded into Q at projection time

typedef __attribute__((ext_vector_type(8))) short short8;   // 8 bf16 (4 VGPRs)
typedef __attribute__((ext_vector_type(4))) float f32x4;    // MFMA C/D

// fp32 -> bf16 bits (RNE)
static __device__ __forceinline__ unsigned short f2b(float f) {
    union { __hip_bfloat16 b; unsigned short u; } cv;
    cv.b = __float2bfloat16(f);
    return cv.u;
}
// packed fp32 pair -> bf16x2 (RNE), lo in low 16 bits
static __device__ __forceinline__ unsigned int pk_bf16(float lo, float hi) {
    union { __hip_bfloat162 v; unsigned int u; } cv;
    cv.v = __float22bfloat162_rn(make_float2(lo, hi));
    return cv.u;
}
// raw v_exp_f32: 1 instruction (no libm fixup)
static __device__ __forceinline__ float exp2_raw(float x) {
#if __has_builtin(__builtin_amdgcn_exp2f)
    return __builtin_amdgcn_exp2f(x);
#else
    float r;
    asm volatile("v_exp_f32 %0, %1" : "=v"(r) : "v"(x));
    return r;
#endif
}
// async global->LDS, 16B per lane; LDS dest = uniform base + lane*16
static __device__ __forceinline__ void load_lds16(const void* g, void* l) {
    __builtin_amdgcn_global_load_lds(
        (const __attribute__((address_space(1))) unsigned int*)g,
        (__attribute__((address_space(3))) unsigned int*)l, 16, 0, 0);
}

// ---------------------------------------------------------------------------
// Kernel 0: prep. Blocks 0..767: Wt[n_cat][k] = W_w[k][n] (bf16) + bias.
// Blocks 768..799: T2 = pad * (-1e9*scale*log2e).
// ---------------------------------------------------------------------------
__global__ __launch_bounds__(256) void prep_kernel(
    const float* __restrict__ Wq, const float* __restrict__ Wk,
    const float* __restrict__ Wv,
    const float* __restrict__ bq, const float* __restrict__ bk,
    const float* __restrict__ bv,
    const float* __restrict__ pad,
    unsigned short* __restrict__ Wt, float* __restrict__ biasc,
    float* __restrict__ T2)
{
    const int blk = blockIdx.x;
    const int t = threadIdx.x;
    if (blk < 768) {
        const int w = blk >> 8;          // 0=Q 1=K 2=V
        const int k = blk & 255;         // input row (contraction index)
        const float* W = (w == 0) ? Wq : (w == 1) ? Wk : Wv;
        Wt[(size_t)(w * 256 + t) * 256 + k] = f2b(W[(size_t)k * 256 + t]);
        if (k == 0) {
            const float* bb = (w == 0) ? bq : (w == 1) ? bk : bv;
            biasc[w * 256 + t] = bb[t];
        }
    } else {
        const int i = (blk - 768) * 256 + t;
        T2[i] = pad[i] * (MASK_BIAS * SCALE * LOG2E);
    }
}

// ---------------------------------------------------------------------------
// Kernel 1: QKV projection as bf16 MFMA GEMM.
// Q output is pre-scaled by QSCALE = SCALE*LOG2E, so the attn kernel's
// QK^T MFMA result is already in exp2-argument units.
// ---------------------------------------------------------------------------
__global__ __launch_bounds__(256) void qkv_mfma_kernel(
    const float* __restrict__ x, const unsigned short* __restrict__ Wt,
    const float* __restrict__ biasc,
    unsigned short* __restrict__ Qh, unsigned short* __restrict__ Kh,
    unsigned short* __restrict__ Vt)
{
    const int lane = threadIdx.x & 63;
    const int wid  = threadIdx.x >> 6;
    const int c    = lane & 15;
    const int quad = lane >> 4;

    const int r0 = (blockIdx.x >> 3) * 64 + wid * 16;   // wave row base
    const int n0 = (blockIdx.x & 7) * 96;               // wave col base

    f32x4 acc[6];
    float bias[6];
    #pragma unroll
    for (int t = 0; t < 6; t++) {
        acc[t] = (f32x4){0.f, 0.f, 0.f, 0.f};
        bias[t] = biasc[n0 + 16 * t + c];
    }

    const float* xp0 = x + (size_t)(r0 + c) * D_MODEL + quad * 8;
    const unsigned short* wp0 = Wt + (size_t)(n0 + c) * 256 + quad * 8;

    for (int k0 = 0; k0 < 256; k0 += 32) {
        const float4 a0 = *(const float4*)(xp0 + k0);
        const float4 a1 = *(const float4*)(xp0 + k0 + 4);
        union { unsigned int u[4]; short8 s; } af;
        af.u[0] = pk_bf16(a0.x, a0.y);
        af.u[1] = pk_bf16(a0.z, a0.w);
        af.u[2] = pk_bf16(a1.x, a1.y);
        af.u[3] = pk_bf16(a1.z, a1.w);
        #pragma unroll
        for (int t = 0; t < 6; t++) {
            const short8 bf = *(const short8*)(wp0 + (size_t)(16 * t) * 256 + k0);
            acc[t] = __builtin_amdgcn_mfma_f32_16x16x32_bf16(af.s, bf, acc[t], 0, 0, 0);
        }
    }

    #pragma unroll
    for (int t = 0; t < 6; t++) {
        const int col = n0 + 16 * t;          // tile col base (multiple of 16)
        const int mm  = col >> 8;             // 0=Q 1=K 2=V (uniform per tile)
        const int dim = (col & 255) + c;
        const int h = dim >> 5, d = dim & 31;
        const int row = r0 + quad * 4;        // rows row..row+3 (same batch)
        const int bb = row >> 12;
        const int s  = row & (SEQ - 1);
        const size_t bh = (size_t)(bb * NUM_HEADS + h);
        float v0 = acc[t][0] + bias[t];
        float v1 = acc[t][1] + bias[t];
        float v2 = acc[t][2] + bias[t];
        float v3 = acc[t][3] + bias[t];
        if (mm == 2) {
            uint2 pk = make_uint2(pk_bf16(v0, v1), pk_bf16(v2, v3));
            *(uint2*)(Vt + (bh * DIM_HEAD + d) * SEQ + s) = pk;
        } else {
            if (mm == 0) {                    // pre-scale Q by SCALE*LOG2E
                v0 *= QSCALE; v1 *= QSCALE; v2 *= QSCALE; v3 *= QSCALE;
            }
            unsigned short* P = (mm == 0 ? Qh : Kh) + (bh * SEQ + s) * DIM_HEAD + d;
            P[0]  = f2b(v0);
            P[32] = f2b(v1);
            P[64] = f2b(v2);
            P[96] = f2b(v3);
        }
    }
}

// ---------------------------------------------------------------------------
// Kernel 2: MFMA flash attention v8 — 32 queries per wave (128 q per block).
// R14 change: each wave owns TWO 16-query tiles (qfA/qfB) sharing every
// K/V/T LDS read -> LDS read bytes per score HALVED (LDS BW was the top
// bottleneck term: ~2.1 GB of b128 reads). Grid halves to 512 blocks
// (2 blocks/CU, 8 waves/CU). Triple-buffered counted-vmcnt pipeline
// (prefetch distance 2, vmcnt never drained to 0 in-loop) unchanged.
// ---------------------------------------------------------------------------
__global__ __launch_bounds__(256, 2) void attn_mfma_kernel(
    const unsigned short* __restrict__ Qh, const unsigned short* __restrict__ Kh,
    const unsigned short* __restrict__ Vt, const float* __restrict__ T2,
    float* __restrict__ O)
{
    __shared__ __align__(16) unsigned short ldsK[3][64 * 32];  // [key][dimgrp] 3x4KB
    __shared__ __align__(16) unsigned short ldsV[3][32 * 64];  // [dim][keygrp] 3x4KB
    __shared__ __align__(16) float          ldsT[3][64];       // 3x256B

    const int lane = threadIdx.x & 63;
    const int wid  = threadIdx.x >> 6;
    const int c    = lane & 15;
    const int quad = lane >> 4;

    const int gw = blockIdx.x;                   // 0..511
    const int q0 = (gw & 31) * 128;              // 128 queries per block
    const int h  = (gw >> 5) & (NUM_HEADS - 1);
    const int b  = gw >> 8;
    const size_t bh = (size_t)(b * NUM_HEADS + h);

    const int perm = ((c & 12) << 1) | (c & 3);  // pi(c)

    const unsigned short* Kb = Kh + bh * SEQ * DIM_HEAD;
    const unsigned short* Vb = Vt + bh * DIM_HEAD * SEQ;
    const float* Tb = T2 + (size_t)b * SEQ;

    // wave's 32 queries: q0 + wid*32 + {c, 16+c}
    const int qrow = q0 + wid * 32;
    const short8 qfA = *(const short8*)(Qh + (bh * SEQ + qrow + c) * DIM_HEAD + quad * 8);
    const short8 qfB = *(const short8*)(Qh + (bh * SEQ + qrow + 16 + c) * DIM_HEAD + quad * 8);

    union { unsigned int u[4]; short8 s; } ones;
    ones.u[0] = ones.u[1] = ones.u[2] = ones.u[3] = 0x3F803F80u;  // bf16 1.0 x2

    // loop-invariant LDS read offsets (elements)
    const int f0 = ((perm >> 1) ^ (perm >> 3)) & 3;
    const int f1 = (((perm + 4) >> 1) ^ ((perm + 4) >> 3)) & 3;
    const int kA = perm * 32 + ((quad ^ f0) << 3);        // + sub*1024
    const int kB = (perm + 4) * 32 + ((quad ^ f1) << 3);
    const int g0 = quad ^ (c & 7);
    const int vA0 = c * 64 + (g0 << 3);
    const int vA1 = c * 64 + ((g0 ^ 4) << 3);
    const int vB0 = (16 + c) * 64 + (g0 << 3);
    const int vB1 = (16 + c) * 64 + ((g0 ^ 4) << 3);

    // staging lane constants
    const int skey = (lane >> 2);                // + j*16
    const int sgK  = lane & 3;
    const int sdim = lane >> 3;                  // + j*8
    const int sgV  = lane & 7;

    f32x4 oA0 = {0.f,0.f,0.f,0.f}, oA1 = {0.f,0.f,0.f,0.f};
    f32x4 oB0 = {0.f,0.f,0.f,0.f}, oB1 = {0.f,0.f,0.f,0.f};
    f32x4 laccA = {0.f,0.f,0.f,0.f}, laccB = {0.f,0.f,0.f,0.f};

    // stage chunk ch into buffer pb (wave-split: w0/w1 -> K, w2/w3 -> V(+T))
    // per-wave vm-op count: wid 0..2 -> 2, wid 3 -> 3
    auto stage = [&](int ch, int pb) {
        const int s0 = ch * 64;
        if (wid < 2) {
            #pragma unroll
            for (int jj = 0; jj < 2; jj++) {
                const int j = wid * 2 + jj;
                const int key = j * 16 + skey;
                const int f = ((key >> 1) ^ (key >> 3)) & 3;
                load_lds16(Kb + (size_t)(s0 + key) * 32 + ((sgK ^ f) << 3),
                           &ldsK[pb][j * 512]);
            }
        } else {
            #pragma unroll
            for (int jj = 0; jj < 2; jj++) {
                const int j = (wid - 2) * 2 + jj;
                const int dim = j * 8 + sdim;
                load_lds16(Vb + (size_t)dim * SEQ + s0 + ((sgV ^ (dim & 7)) << 3),
                           &ldsV[pb][j * 512]);
            }
            if (wid == 3 && lane < 16)
                load_lds16(Tb + s0 + lane * 4, &ldsT[pb][0]);
        }
    };

    // one 32-key sub-chunk from LDS buffer pb; T folded in as MFMA C operand.
    // K/V/T fragments read ONCE, used by both q-tiles.
    auto sub = [&](int pb, int s) {
        const short8 kf0 = *(const short8*)&ldsK[pb][s * 1024 + kA];
        const short8 kf1 = *(const short8*)&ldsK[pb][s * 1024 + kB];
        const short8 vf0 = *(const short8*)&ldsV[pb][s ? vA1 : vA0];
        const short8 vf1 = *(const short8*)&ldsV[pb][s ? vB1 : vB0];
        const float4 t0 = *(const float4*)&ldsT[pb][s * 32 + quad * 8];
        const float4 t1 = *(const float4*)&ldsT[pb][s * 32 + quad * 8 + 4];

        const f32x4 c0 = {t0.x, t0.y, t0.z, t0.w};
        const f32x4 c1 = {t1.x, t1.y, t1.z, t1.w};

        const f32x4 sA0 = __builtin_amdgcn_mfma_f32_16x16x32_bf16(kf0, qfA, c0, 0, 0, 0);
        const f32x4 sA1 = __builtin_amdgcn_mfma_f32_16x16x32_bf16(kf1, qfA, c1, 0, 0, 0);
        const f32x4 sB0 = __builtin_amdgcn_mfma_f32_16x16x32_bf16(kf0, qfB, c0, 0, 0, 0);
        const f32x4 sB1 = __builtin_amdgcn_mfma_f32_16x16x32_bf16(kf1, qfB, c1, 0, 0, 0);

        union { unsigned int u[4]; short8 s8; } pfA, pfB;
        {
            float p0 = exp2_raw(sA0[0]), p1 = exp2_raw(sA0[1]);
            float p2 = exp2_raw(sA0[2]), p3 = exp2_raw(sA0[3]);
            float p4 = exp2_raw(sA1[0]), p5 = exp2_raw(sA1[1]);
            float p6 = exp2_raw(sA1[2]), p7 = exp2_raw(sA1[3]);
            pfA.u[0] = pk_bf16(p0, p1);
            pfA.u[1] = pk_bf16(p2, p3);
            pfA.u[2] = pk_bf16(p4, p5);
            pfA.u[3] = pk_bf16(p6, p7);
        }
        {
            float p0 = exp2_raw(sB0[0]), p1 = exp2_raw(sB0[1]);
            float p2 = exp2_raw(sB0[2]), p3 = exp2_raw(sB0[3]);
            float p4 = exp2_raw(sB1[0]), p5 = exp2_raw(sB1[1]);
            float p6 = exp2_raw(sB1[2]), p7 = exp2_raw(sB1[3]);
            pfB.u[0] = pk_bf16(p0, p1);
            pfB.u[1] = pk_bf16(p2, p3);
            pfB.u[2] = pk_bf16(p4, p5);
            pfB.u[3] = pk_bf16(p6, p7);
        }

        laccA = __builtin_amdgcn_mfma_f32_16x16x32_bf16(ones.s, pfA.s8, laccA, 0, 0, 0);
        laccB = __builtin_amdgcn_mfma_f32_16x16x32_bf16(ones.s, pfB.s8, laccB, 0, 0, 0);
        oA0   = __builtin_amdgcn_mfma_f32_16x16x32_bf16(vf0,   pfA.s8, oA0,   0, 0, 0);
        oA1   = __builtin_amdgcn_mfma_f32_16x16x32_bf16(vf1,   pfA.s8, oA1,   0, 0, 0);
        oB0   = __builtin_amdgcn_mfma_f32_16x16x32_bf16(vf0,   pfB.s8, oB0,   0, 0, 0);
        oB1   = __builtin_amdgcn_mfma_f32_16x16x32_bf16(vf1,   pfB.s8, oB1,   0, 0, 0);
    };

    // prologue: prefetch chunks 0 and 1
    stage(0, 0);
    stage(1, 1);

    int rb = 0;          // read buffer  = ch % 3
    int sb = 2;          // stage buffer = (ch+2) % 3
    for (int ch = 0; ch < SEQ / 64; ++ch) {
        // wait for MY stage(ch) loads (allow the newer stage(ch+1) to remain
        // in flight); lgkmcnt(0) ensures all my LDS reads of buf[(ch-1)%3]
        // executed before I arrive at the barrier.
        if (wid == 3)
            asm volatile("s_waitcnt vmcnt(3) lgkmcnt(0)" ::: "memory");
        else
            asm volatile("s_waitcnt vmcnt(2) lgkmcnt(0)" ::: "memory");
        __builtin_amdgcn_s_barrier();
        __builtin_amdgcn_sched_barrier(0);
        // all waves' stage(ch) visible; all waves done reading buf[(ch-1)%3]
        stage((ch + 2) & 63, sb);        // overwrite buf[(ch-1)%3]
        sub(rb, 0);
        sub(rb, 1);
        rb = (rb == 2) ? 0 : rb + 1;
        sb = (sb == 2) ? 0 : sb + 1;
    }

    // normalize + store: every lane's lacc[0] = denominator of query col c
    const float invA = 1.0f / laccA[0];
    const float invB = 1.0f / laccB[0];
    float* opA = O + ((size_t)(b * SEQ) + qrow + c) * D_MODEL + h * DIM_HEAD + quad * 4;
    float* opB = O + ((size_t)(b * SEQ) + qrow + 16 + c) * D_MODEL + h * DIM_HEAD + quad * 4;
    *(float4*)opA        = make_float4(oA0[0]*invA, oA0[1]*invA, oA0[2]*invA, oA0[3]*invA);
    *(float4*)(opA + 16) = make_float4(oA1[0]*invA, oA1[1]*invA, oA1[2]*invA, oA1[3]*invA);
    *(float4*)opB        = make_float4(oB0[0]*invB, oB0[1]*invB, oB0[2]*invB, oB0[3]*invB);
    *(float4*)(opB + 16) = make_float4(oB1[0]*invB, oB1[1]*invB, oB1[2]*invB, oB1[3]*invB);
}

// ---------------------------------------------------------------------------
// Kernel 3: residual add + LayerNorm IN PLACE on d_out (fp32 -> fp32).
// ---------------------------------------------------------------------------
__global__ __launch_bounds__(256) void ln_kernel(
    float* AO,                     // aliased read A / write out — no restrict
    const float* __restrict__ x,
    const float* __restrict__ gamma, const float* __restrict__ beta)
{
    const int lane = threadIdx.x & 63;
    const int wid  = threadIdx.x >> 6;
    const size_t row = (size_t)blockIdx.x * 4 + wid;

    const float4 a  = ((const float4*)(AO + row * D_MODEL))[lane];
    const float4 xv = ((const float4*)(x + row * D_MODEL))[lane];
    float hv[4];
    hv[0] = a.x + xv.x;
    hv[1] = a.y + xv.y;
    hv[2] = a.z + xv.z;
    hv[3] = a.w + xv.w;

    float s = hv[0] + hv[1] + hv[2] + hv[3];
    #pragma unroll
    for (int off = 32; off > 0; off >>= 1) s += __shfl_xor(s, off, 64);
    const float mu = s * (1.0f / D_MODEL);

    float d0 = hv[0]-mu, d1 = hv[1]-mu, d2 = hv[2]-mu, d3 = hv[3]-mu;
    float ss = d0*d0 + d1*d1 + d2*d2 + d3*d3;
    #pragma unroll
    for (int off = 32; off > 0; off >>= 1) ss += __shfl_xor(ss, off, 64);
    const float rs = rsqrtf(ss * (1.0f / D_MODEL) + LN_EPS);

    const float4 g  = ((const float4*)gamma)[lane];
    const float4 bb = ((const float4*)beta)[lane];
    float4 y;
    y.x = g.x * d0 * rs + bb.x;
    y.y = g.y * d1 * rs + bb.y;
    y.z = g.z * d2 * rs + bb.z;
    y.w = g.w * d3 * rs + bb.w;
    ((float4*)(AO + row * D_MODEL))[lane] = y;
}

// ---------------------------------------------------------------------------
extern "C" void kernel_launch(void* const* d_in, const int* in_sizes, int n_in,
                              void* d_out, int out_size, void* d_ws, size_t ws_size,
                              hipStream_t stream)
{
    const float* x     = (const float*)d_in[0];
    const float* pad   = (const float*)d_in[1];
    const float* Wq    = (const float*)d_in[2];
    const float* bq    = (const float*)d_in[3];
    const float* Wk    = (const float*)d_in[4];
    const float* bk    = (const float*)d_in[5];
    const float* Wv    = (const float*)d_in[6];
    const float* bv    = (const float*)d_in[7];
    const float* gamma = (const float*)d_in[8];
    const float* beta  = (const float*)d_in[9];

    const size_t elems = (size_t)NROWS * D_MODEL;       // 2M
    unsigned short* Qh = (unsigned short*)d_ws;          // 4 MB
    unsigned short* Kh = Qh + elems;                     // 4 MB
    unsigned short* Vt = Kh + elems;                     // 4 MB
    float* T2 = (float*)(Vt + elems);                    // 32 KB
    unsigned short* Wt = (unsigned short*)(T2 + NROWS);  // 768x256 bf16, 384 KB
    float* biasc = (float*)(Wt + 768 * 256);             // 3 KB
    float* AO = (float*)d_out;                           // attn out + final out

    prep_kernel<<<800, 256, 0, stream>>>(Wq, Wk, Wv, bq, bk, bv, pad,
                                         Wt, biasc, T2);
    qkv_mfma_kernel<<<(NROWS / 64) * 8, 256, 0, stream>>>(x, Wt, biasc,
                                                          Qh, Kh, Vt);
    attn_mfma_kernel<<<BATCH * NUM_HEADS * (SEQ / 128), 256, 0, stream>>>(
        Qh, Kh, Vt, T2, AO);
    ln_kernel<<<NROWS / 4, 256, 0, stream>>>(AO, x, gamma, beta);
}